// Round 4
// baseline (19.223 us; speedup 1.0000x reference)
//
#include <hip/hip_runtime.h>
#include <hip/hip_fp16.h>
#include <math.h>

#define SEQ_L 4096
#define THREADS 512
#define WAVES 8
#define BLOCKS_PER_BATCH 256   // 256 blocks * 8 waves = 2048 row-pairs per batch

__global__ __launch_bounds__(THREADS, 8) void attn_rows_kernel(
    const float* __restrict__ x,
    const float* __restrict__ q_weight,
    const float* __restrict__ v_weight,
    const float* __restrict__ gate_weight,
    const float* __restrict__ carry_weight,
    float* __restrict__ out,
    float scaleL2,           // SCALE * log2(e)
    float cd, float sd,      // cos(256*omega), sin(256*omega)
    float ck1, float sk1,    // cos(k*omega), sin(k*omega), k=1..3
    float ck2, float sk2,
    float ck3, float sk3)
{
    __shared__ __half2 aw[SEQ_L];   // 16 KB packed (a_j, w_j)

    const int tid  = threadIdx.x;
    const int lane = tid & 63;
    const int wave = tid >> 6;
    const int b    = blockIdx.x >> 8;    // / BLOCKS_PER_BATCH
    const int bb   = blockIdx.x & 255;

    const float phi = q_weight[0];
    const float vw  = v_weight[0];
    const float2* x2 = (const float2*)x + (size_t)b * SEQ_L;

    // cos(phi), sin(phi) via hardware trig (input in revolutions)
    const float INV2PI = 0.15915494309189535f;
    const float rphi = phi * INV2PI;                  // |phi| < ~0.5 rad -> in range
    const float cphi = __builtin_amdgcn_cosf(rphi);
    const float sphi = __builtin_amdgcn_sinf(rphi);

    // Phase 0: stage packed (a_j, w_j) into LDS
    for (int j = tid; j < SEQ_L; j += THREADS) {
        float2 xv = x2[j];
        float inv = __builtin_amdgcn_rsqf(
                        fmaf(xv.x, xv.x * 0.5f, fmaf(xv.y, xv.y * 0.5f, 1e-6f)));
        float xn0 = xv.x * inv;
        float xn1 = xv.y * inv;
        float a = xn0 * __builtin_amdgcn_rsqf(fmaf(xn0, xn0 * 0.5f, 1e-6f));
        aw[j] = __floats2half2_rn(a, xn1 * vw);
    }
    __syncthreads();

    const float ga = gate_weight[0];
    const float gc = gate_weight[1];
    const float cw = carry_weight[0];

    const int v = bb * WAVES + wave;     // 0..2047
    const float SQRT2 = 1.4142135623730951f;
    const float LOG2E = 1.4426950408889634f;
    const float INV19 = 1.0f / 19.0f;

    #pragma unroll
    for (int rr = 0; rr < 2; ++rr) {
        const int i = (rr == 0) ? v : (SEQ_L - 1 - v);   // wave-uniform

        const float2 xv = x2[i];                 // prefetch: epilogue + exact t2
        float invx = __builtin_amdgcn_rsqf(
                        fmaf(xv.x, xv.x * 0.5f, fmaf(xv.y, xv.y * 0.5f, 1e-6f)));
        float xn0i = xv.x * invx;
        float a_i  = xn0i * __builtin_amdgcn_rsqf(fmaf(xn0i, xn0i * 0.5f, 1e-6f));
        const float t2 = scaleL2 * a_i;
        const float M2 = fabsf(t2) * SQRT2;      // static per-row max bound (log2)

        // initial angle: theta = omega*r - phi, r = (i - 4*lane) mod 19
        unsigned r = (unsigned)(i - (lane << 2) + 266) % 19u;   // 266 = 14*19
        float rev = (float)r * INV19;            // exact-ish, < 1 revolution
        float cr = __builtin_amdgcn_cosf(rev);   // cos(omega*r)
        float sr = __builtin_amdgcn_sinf(rev);
        float c0 = fmaf(sr, sphi, cr * cphi);    // cos(omega*r - phi)
        float s0 = fmaf(cr, -sphi, sr * cphi);   // sin(omega*r - phi)
        float C = t2 * c0;
        float S = t2 * s0;

        float sA = 0.f, sB = 0.f, oA = 0.f, oB = 0.f;
        int jb = lane << 2;                      // element index, this lane
        const int nfull = (i + 1) >> 8;          // wave-uniform

        for (int k = 0; k < nfull; ++k) {
            float4 raw = *(const float4*)&aw[jb];    // one ds_read_b128: 4 half2
            const __half2* hp = (const __half2*)&raw;
            float2 p0 = __half22float2(hp[0]);
            float2 p1 = __half22float2(hp[1]);
            float2 p2 = __half22float2(hp[2]);
            float2 p3 = __half22float2(hp[3]);
            float C1 = fmaf(S, sk1, C * ck1);
            float C2 = fmaf(S, sk2, C * ck2);
            float C3 = fmaf(S, sk3, C * ck3);
            float e0 = __builtin_amdgcn_exp2f(fmaf(p0.x, C,  -M2));
            float e1 = __builtin_amdgcn_exp2f(fmaf(p1.x, C1, -M2));
            float e2 = __builtin_amdgcn_exp2f(fmaf(p2.x, C2, -M2));
            float e3 = __builtin_amdgcn_exp2f(fmaf(p3.x, C3, -M2));
            sA += e0 + e1;
            sB += e2 + e3;
            oA = fmaf(e0, p0.y, oA);
            oB = fmaf(e1, p1.y, oB);
            oA = fmaf(e2, p2.y, oA);
            oB = fmaf(e3, p3.y, oB);
            float Cn = fmaf(S, sd, C * cd);      // rotate by -256*omega
            float Sn = fmaf(S, cd, -(C * sd));
            C = Cn; S = Sn;
            jb += 256;
        }
        if ((i & 255) != 255) {                  // masked tail (wave-uniform guard)
            float4 raw = *(const float4*)&aw[jb];
            const __half2* hp = (const __half2*)&raw;
            float2 p0 = __half22float2(hp[0]);
            float2 p1 = __half22float2(hp[1]);
            float2 p2 = __half22float2(hp[2]);
            float2 p3 = __half22float2(hp[3]);
            float C1 = fmaf(S, sk1, C * ck1);
            float C2 = fmaf(S, sk2, C * ck2);
            float C3 = fmaf(S, sk3, C * ck3);
            float e0 = __builtin_amdgcn_exp2f(fmaf(p0.x, C,  -M2));
            float e1 = __builtin_amdgcn_exp2f(fmaf(p1.x, C1, -M2));
            float e2 = __builtin_amdgcn_exp2f(fmaf(p2.x, C2, -M2));
            float e3 = __builtin_amdgcn_exp2f(fmaf(p3.x, C3, -M2));
            e0 = (jb + 0 <= i) ? e0 : 0.f;
            e1 = (jb + 1 <= i) ? e1 : 0.f;
            e2 = (jb + 2 <= i) ? e2 : 0.f;
            e3 = (jb + 3 <= i) ? e3 : 0.f;
            sA += e0 + e1;
            sB += e2 + e3;
            oA = fmaf(e0, p0.y, oA);
            oB = fmaf(e1, p1.y, oB);
            oA = fmaf(e2, p2.y, oA);
            oB = fmaf(e3, p3.y, oB);
        }

        float ssum = sA + sB;
        float osum = oA + oB;
        for (int off = 32; off > 0; off >>= 1) {
            ssum += __shfl_xor(ssum, off);
            osum += __shfl_xor(osum, off);
        }

        if (lane == 0) {
            float o0 = osum * __builtin_amdgcn_rcpf(ssum);
            float h0 = xv.x;
            float h1 = xv.y + o0;
            float inv = __builtin_amdgcn_rsqf(
                           fmaf(h0, h0 * 0.5f, fmaf(h1, h1 * 0.5f, 1e-6f)));
            float hn0 = h0 * inv, hn1 = h1 * inv;
            float g0 = hn0 * ga + hn1 * gc;
            float g1 = hn0 * (ga - gc * 1e-3f) + hn1 * gc;
            float sig0 = __builtin_amdgcn_rcpf(1.f + __builtin_amdgcn_exp2f(-g0 * LOG2E));
            float sig1 = __builtin_amdgcn_rcpf(1.f + __builtin_amdgcn_exp2f(-g1 * LOG2E));
            float mix0 = g0 * sig0 * hn0;
            float mix1 = g1 * sig1 * hn0;
            float y1 = cw * (mix1 - mix0);
            float2* outp = (float2*)out + (size_t)b * SEQ_L + i;
            *outp = make_float2(xv.x, h1 + y1);
        }
    }
}

extern "C" void kernel_launch(void* const* d_in, const int* in_sizes, int n_in,
                              void* d_out, int out_size, void* d_ws, size_t ws_size,
                              hipStream_t stream)
{
    const float* x  = (const float*)d_in[0];
    // d_in[1] = mask — causality handled analytically, unused
    const float* qw = (const float*)d_in[2];
    const float* vw = (const float*)d_in[3];
    const float* gw = (const float*)d_in[4];
    const float* cw = (const float*)d_in[5];
    float* out = (float*)d_out;

    const double omega = 2.0 * M_PI / 19.0;
    const double amp   = log(10.0) / (cos(omega * 0.3) - cos(omega * 0.7));
    const double qkns2 = amp / sqrt(2.0);               // QK_NORM_SCALE^2
    const double scale = pow(2.0, -0.5) * qkns2;        // HEAD_DIM^-0.5 * QK_NORM_SCALE^2
    const double L2E   = 1.4426950408889634074;
    const double delta = 256.0 * omega;                 // per-iteration angle decrement

    attn_rows_kernel<<<dim3(4 * BLOCKS_PER_BATCH), dim3(THREADS), 0, stream>>>(
        x, qw, vw, gw, cw, out,
        (float)(scale * L2E),
        (float)cos(delta),       (float)sin(delta),
        (float)cos(omega),       (float)sin(omega),
        (float)cos(2.0 * omega), (float)sin(2.0 * omega),
        (float)cos(3.0 * omega), (float)sin(3.0 * omega));
}

// Round 5
// 18.408 us; speedup vs baseline: 1.0443x; 1.0443x over previous
//
#include <hip/hip_runtime.h>
#include <hip/hip_fp16.h>
#include <math.h>

#define SEQ_L 4096
#define THREADS 512

// 6-step gfx9 DPP wave64 sum; result valid in lane 63.
__device__ __forceinline__ float wave_sum_dpp(float x) {
    int t;
    t = __builtin_amdgcn_update_dpp(0, __float_as_int(x), 0x111, 0xf, 0xf, true); x += __int_as_float(t);
    t = __builtin_amdgcn_update_dpp(0, __float_as_int(x), 0x112, 0xf, 0xf, true); x += __int_as_float(t);
    t = __builtin_amdgcn_update_dpp(0, __float_as_int(x), 0x114, 0xf, 0xf, true); x += __int_as_float(t);
    t = __builtin_amdgcn_update_dpp(0, __float_as_int(x), 0x118, 0xf, 0xf, true); x += __int_as_float(t);
    t = __builtin_amdgcn_update_dpp(0, __float_as_int(x), 0x142, 0xa, 0xf, true); x += __int_as_float(t);
    t = __builtin_amdgcn_update_dpp(0, __float_as_int(x), 0x143, 0xc, 0xf, true); x += __int_as_float(t);
    return x;
}

// Process one group of 4 rows {b, b+19, b+38, b+57} (shared mod-19 cos class).
__device__ __forceinline__ void do_group(
    int g, int lane, const float2* __restrict__ x2, const __half2* aw,
    float2* __restrict__ outp, float scaleL2, float cphi, float sphi,
    float cd, float sd, float ck1, float sk1, float ck2, float sk2,
    float ck3, float sk3, float ga, float gc, float cw)
{
    const float INV19 = 1.0f / 19.0f;
    const float LOG2E = 1.4426950408889634f;

    int m  = g / 19;
    int c  = g - 19 * m;
    int b0 = 76 * m + c;
    int i0r = b0, i1r = b0 + 19, i2r = b0 + 38, i3r = b0 + 57;

    float t2a0, t2a1, t2a2, t2a3, M2a0, M2a1, M2a2, M2a3;
#define ROWINIT(tk, Mk, ik) { \
    int ic_ = (ik) < SEQ_L ? (ik) : (SEQ_L - 1); \
    float2 xv_ = x2[ic_]; \
    float inv_ = __builtin_amdgcn_rsqf(fmaf(xv_.x, xv_.x*0.5f, fmaf(xv_.y, xv_.y*0.5f, 1e-6f))); \
    float xn0_ = xv_.x * inv_; \
    float ai_  = xn0_ * __builtin_amdgcn_rsqf(fmaf(xn0_, xn0_*0.5f, 1e-6f)); \
    tk = scaleL2 * ai_;  Mk = fabsf(tk) * 1.4142135623730951f; }
    ROWINIT(t2a0, M2a0, i0r)
    ROWINIT(t2a1, M2a1, i1r)
    ROWINIT(t2a2, M2a2, i2r)
    ROWINIT(t2a3, M2a3, i3r)
#undef ROWINIT

    // shared angle state: theta = omega*((b0 - 4*lane) mod 19) - phi
    unsigned r = (unsigned)(b0 - (lane << 2) + 266) % 19u;   // 266 = 14*19
    float rev = (float)r * INV19;
    float crv = __builtin_amdgcn_cosf(rev);
    float srv = __builtin_amdgcn_sinf(rev);
    float C = fmaf(srv, sphi, crv * cphi);
    float S = fmaf(crv, -sphi, srv * cphi);

    float sa0=0.f, sa1=0.f, sa2=0.f, sa3=0.f;
    float oa0=0.f, oa1=0.f, oa2=0.f, oa3=0.f;
    int jb = lane << 2;
    const int ncom = (b0 + 1) >> 8;
    const int i3c  = i3r < SEQ_L ? i3r : (SEQ_L - 1);
    const int T    = (i3c >> 8) + 1;

#define EL(u, pw) { \
    float e0_ = __builtin_amdgcn_exp2f(fmaf(t2a0, (u), -M2a0)); \
    float e1_ = __builtin_amdgcn_exp2f(fmaf(t2a1, (u), -M2a1)); \
    float e2_ = __builtin_amdgcn_exp2f(fmaf(t2a2, (u), -M2a2)); \
    float e3_ = __builtin_amdgcn_exp2f(fmaf(t2a3, (u), -M2a3)); \
    sa0 += e0_; oa0 = fmaf(e0_, (pw), oa0); \
    sa1 += e1_; oa1 = fmaf(e1_, (pw), oa1); \
    sa2 += e2_; oa2 = fmaf(e2_, (pw), oa2); \
    sa3 += e3_; oa3 = fmaf(e3_, (pw), oa3); }
#define ELM(u, pw, jj) { \
    float e0_ = __builtin_amdgcn_exp2f(fmaf(t2a0, (u), -M2a0)); \
    float e1_ = __builtin_amdgcn_exp2f(fmaf(t2a1, (u), -M2a1)); \
    float e2_ = __builtin_amdgcn_exp2f(fmaf(t2a2, (u), -M2a2)); \
    float e3_ = __builtin_amdgcn_exp2f(fmaf(t2a3, (u), -M2a3)); \
    e0_ = ((jj) <= i0r) ? e0_ : 0.f; \
    e1_ = ((jj) <= i1r) ? e1_ : 0.f; \
    e2_ = ((jj) <= i2r) ? e2_ : 0.f; \
    e3_ = ((jj) <= i3r) ? e3_ : 0.f; \
    sa0 += e0_; oa0 = fmaf(e0_, (pw), oa0); \
    sa1 += e1_; oa1 = fmaf(e1_, (pw), oa1); \
    sa2 += e2_; oa2 = fmaf(e2_, (pw), oa2); \
    sa3 += e3_; oa3 = fmaf(e3_, (pw), oa3); }

    int t = 0;
    for (; t < ncom; ++t) {
        float4 raw = *(const float4*)&aw[jb];
        const __half2* hp = (const __half2*)&raw;
        float2 p0 = __half22float2(hp[0]);
        float2 p1 = __half22float2(hp[1]);
        float2 p2 = __half22float2(hp[2]);
        float2 p3 = __half22float2(hp[3]);
        float C1 = fmaf(S, sk1, C * ck1);
        float C2 = fmaf(S, sk2, C * ck2);
        float C3 = fmaf(S, sk3, C * ck3);
        float u0 = p0.x * C,  u1 = p1.x * C1, u2 = p2.x * C2, u3 = p3.x * C3;
        EL(u0, p0.y) EL(u1, p1.y) EL(u2, p2.y) EL(u3, p3.y)
        float Cn = fmaf(S, sd, C * cd);
        float Sn = fmaf(S, cd, -(C * sd));
        C = Cn; S = Sn;
        jb += 256;
    }
    for (; t < T; ++t) {
        float4 raw = *(const float4*)&aw[jb];
        const __half2* hp = (const __half2*)&raw;
        float2 p0 = __half22float2(hp[0]);
        float2 p1 = __half22float2(hp[1]);
        float2 p2 = __half22float2(hp[2]);
        float2 p3 = __half22float2(hp[3]);
        float C1 = fmaf(S, sk1, C * ck1);
        float C2 = fmaf(S, sk2, C * ck2);
        float C3 = fmaf(S, sk3, C * ck3);
        float u0 = p0.x * C,  u1 = p1.x * C1, u2 = p2.x * C2, u3 = p3.x * C3;
        ELM(u0, p0.y, jb)     ELM(u1, p1.y, jb + 1)
        ELM(u2, p2.y, jb + 2) ELM(u3, p3.y, jb + 3)
        float Cn = fmaf(S, sd, C * cd);
        float Sn = fmaf(S, cd, -(C * sd));
        C = Cn; S = Sn;
        jb += 256;
    }
#undef EL
#undef ELM

    float S0 = wave_sum_dpp(sa0), O0 = wave_sum_dpp(oa0);
    float S1 = wave_sum_dpp(sa1), O1 = wave_sum_dpp(oa1);
    float S2 = wave_sum_dpp(sa2), O2 = wave_sum_dpp(oa2);
    float S3 = wave_sum_dpp(sa3), O3 = wave_sum_dpp(oa3);

    if (lane == 63) {
#define EPI(Sk, Ok, ik) if ((ik) < SEQ_L) { \
    float2 xv_ = x2[ik]; \
    float o0_ = (Ok) * __builtin_amdgcn_rcpf(Sk); \
    float h0_ = xv_.x, h1_ = xv_.y + o0_; \
    float inv_ = __builtin_amdgcn_rsqf(fmaf(h0_, h0_*0.5f, fmaf(h1_, h1_*0.5f, 1e-6f))); \
    float hn0_ = h0_ * inv_, hn1_ = h1_ * inv_; \
    float g0_ = hn0_ * ga + hn1_ * gc; \
    float g1_ = hn0_ * (ga - gc * 1e-3f) + hn1_ * gc; \
    float sg0_ = __builtin_amdgcn_rcpf(1.f + __builtin_amdgcn_exp2f(-g0_ * LOG2E)); \
    float sg1_ = __builtin_amdgcn_rcpf(1.f + __builtin_amdgcn_exp2f(-g1_ * LOG2E)); \
    float y1_ = cw * (g1_ * sg1_ - g0_ * sg0_) * hn0_; \
    outp[ik] = make_float2(h0_, h1_ + y1_); }
        EPI(S0, O0, i0r)
        EPI(S1, O1, i1r)
        EPI(S2, O2, i2r)
        EPI(S3, O3, i3r)
#undef EPI
    }
}

__global__ __launch_bounds__(THREADS, 4) void attn_rows_kernel(
    const float* __restrict__ x,
    const float* __restrict__ q_weight,
    const float* __restrict__ v_weight,
    const float* __restrict__ gate_weight,
    const float* __restrict__ carry_weight,
    float* __restrict__ out,
    float scaleL2,
    float cd, float sd,
    float ck1, float sk1, float ck2, float sk2, float ck3, float sk3)
{
    __shared__ __half2 aw[SEQ_L];   // 16 KB packed (a_j, w_j)

    const int tid  = threadIdx.x;
    const int lane = tid & 63;
    const int wave = tid >> 6;
    const int bat  = blockIdx.x >> 7;     // 128 blocks per batch
    const int bb   = blockIdx.x & 127;

    const float phi = q_weight[0];
    const float vw  = v_weight[0];
    const float2* x2 = (const float2*)x + (size_t)bat * SEQ_L;
    float2* outp = (float2*)out + (size_t)bat * SEQ_L;

    const float INV2PI = 0.15915494309189535f;
    const float rphi = phi * INV2PI;
    const float cphi = __builtin_amdgcn_cosf(rphi);
    const float sphi = __builtin_amdgcn_sinf(rphi);

    for (int j = tid; j < SEQ_L; j += THREADS) {
        float2 xv = x2[j];
        float inv = __builtin_amdgcn_rsqf(
                        fmaf(xv.x, xv.x * 0.5f, fmaf(xv.y, xv.y * 0.5f, 1e-6f)));
        float xn0 = xv.x * inv;
        float xn1 = xv.y * inv;
        float a = xn0 * __builtin_amdgcn_rsqf(fmaf(xn0, xn0 * 0.5f, 1e-6f));
        aw[j] = __floats2half2_rn(a, xn1 * vw);
    }
    __syncthreads();

    const float ga = gate_weight[0];
    const float gc = gate_weight[1];
    const float cw = carry_weight[0];

    // balanced assignment: q = bb + 128*wave in [0,1024);
    // g = q (q<513) else 1538-q; waves q==511/512 pick up leftover groups 514/513.
    const int q = bb + (wave << 7);
    const int g = (q < 513) ? q : (1538 - q);

    do_group(g, lane, x2, aw, outp, scaleL2, cphi, sphi,
             cd, sd, ck1, sk1, ck2, sk2, ck3, sk3, ga, gc, cw);
    if (q == 511)
        do_group(514, lane, x2, aw, outp, scaleL2, cphi, sphi,
                 cd, sd, ck1, sk1, ck2, sk2, ck3, sk3, ga, gc, cw);
    else if (q == 512)
        do_group(513, lane, x2, aw, outp, scaleL2, cphi, sphi,
                 cd, sd, ck1, sk1, ck2, sk2, ck3, sk3, ga, gc, cw);
}

extern "C" void kernel_launch(void* const* d_in, const int* in_sizes, int n_in,
                              void* d_out, int out_size, void* d_ws, size_t ws_size,
                              hipStream_t stream)
{
    const float* x  = (const float*)d_in[0];
    // d_in[1] = mask — causality handled analytically, unused
    const float* qw = (const float*)d_in[2];
    const float* vw = (const float*)d_in[3];
    const float* gw = (const float*)d_in[4];
    const float* cw = (const float*)d_in[5];
    float* out = (float*)d_out;

    const double omega = 2.0 * M_PI / 19.0;
    const double amp   = log(10.0) / (cos(omega * 0.3) - cos(omega * 0.7));
    const double qkns2 = amp / sqrt(2.0);               // QK_NORM_SCALE^2
    const double scale = pow(2.0, -0.5) * qkns2;        // HEAD_DIM^-0.5 * QK_NORM_SCALE^2
    const double L2E   = 1.4426950408889634074;
    const double delta = 256.0 * omega;                 // per-iteration angle decrement

    attn_rows_kernel<<<dim3(4 * 128), dim3(THREADS), 0, stream>>>(
        x, qw, vw, gw, cw, out,
        (float)(scale * L2E),
        (float)cos(delta),       (float)sin(delta),
        (float)cos(omega),       (float)sin(omega),
        (float)cos(2.0 * omega), (float)sin(2.0 * omega),
        (float)cos(3.0 * omega), (float)sin(3.0 * omega));
}

// Round 6
// 18.318 us; speedup vs baseline: 1.0494x; 1.0049x over previous
//
#include <hip/hip_runtime.h>
#include <math.h>

#define SEQ_L 4096
#define LDS_PAD 260          // covers prefetch over-read past the last iteration

// 6-step gfx9 DPP wave64 sum; result valid in lane 63. (verified R5)
__device__ __forceinline__ float wave_sum_dpp(float x) {
    int t;
    t = __builtin_amdgcn_update_dpp(0, __float_as_int(x), 0x111, 0xf, 0xf, true); x += __int_as_float(t);
    t = __builtin_amdgcn_update_dpp(0, __float_as_int(x), 0x112, 0xf, 0xf, true); x += __int_as_float(t);
    t = __builtin_amdgcn_update_dpp(0, __float_as_int(x), 0x114, 0xf, 0xf, true); x += __int_as_float(t);
    t = __builtin_amdgcn_update_dpp(0, __float_as_int(x), 0x118, 0xf, 0xf, true); x += __int_as_float(t);
    t = __builtin_amdgcn_update_dpp(0, __float_as_int(x), 0x142, 0xa, 0xf, true); x += __int_as_float(t);
    t = __builtin_amdgcn_update_dpp(0, __float_as_int(x), 0x143, 0xc, 0xf, true); x += __int_as_float(t);
    return x;
}

// One group of 4 rows {b0, b0+19, b0+38, b0+57} sharing a mod-19 cos class.
__device__ __forceinline__ void do_group(
    int b0, int lane, const float2* __restrict__ x2,
    const float* As, const float* Ws, float2* __restrict__ outp,
    float scaleL2, float cphi, float sphi,
    float cd, float sd, float ck1, float sk1, float ck2, float sk2,
    float ck3, float sk3, float ga, float gc, float cw)
{
    const float LOG2E = 1.4426950408889634f;
    const float SQRT2 = 1.4142135623730951f;
    const int i0 = b0, i1 = b0 + 19, i2 = b0 + 38, i3 = b0 + 57;
    const int c1 = i1 < SEQ_L ? i1 : SEQ_L - 1;
    const int c2 = i2 < SEQ_L ? i2 : SEQ_L - 1;
    const int c3 = i3 < SEQ_L ? i3 : SEQ_L - 1;

    // per-row scale from LDS broadcast (identical to staged value)
    const float t20 = scaleL2 * As[i0], t21 = scaleL2 * As[c1];
    const float t22 = scaleL2 * As[c2], t23 = scaleL2 * As[c3];
    const float M20 = fabsf(t20) * SQRT2, M21 = fabsf(t21) * SQRT2;
    const float M22 = fabsf(t22) * SQRT2, M23 = fabsf(t23) * SQRT2;

    // epilogue inputs prefetched now; consumed ~whole loop later
    const float2 xv0 = x2[i0], xv1 = x2[c1], xv2 = x2[c2], xv3 = x2[c3];

    // shared angle state: theta = omega*((b0 - 4*lane) mod 19) - phi
    unsigned r = (unsigned)(b0 - (lane << 2) + 266) % 19u;   // 266 = 14*19
    float rev = (float)r * (1.0f / 19.0f);
    float crv = __builtin_amdgcn_cosf(rev);
    float srv = __builtin_amdgcn_sinf(rev);
    float C = fmaf(srv, sphi, crv * cphi);
    float S = fmaf(crv, -sphi, srv * cphi);

    float sa0=0.f, sa1=0.f, sa2=0.f, sa3=0.f;
    float oa0=0.f, oa1=0.f, oa2=0.f, oa3=0.f;
    int jb = lane << 2;
    const int ncom = (b0 + 1) >> 8;      // fully-unmasked iterations
    const int T    = (c3 >> 8) + 1;      // total iterations

#define EL4(u, pw) { \
    float e0_ = __builtin_amdgcn_exp2f(fmaf(t20, (u), -M20)); \
    float e1_ = __builtin_amdgcn_exp2f(fmaf(t21, (u), -M21)); \
    float e2_ = __builtin_amdgcn_exp2f(fmaf(t22, (u), -M22)); \
    float e3_ = __builtin_amdgcn_exp2f(fmaf(t23, (u), -M23)); \
    sa0 += e0_; oa0 = fmaf(e0_, (pw), oa0); \
    sa1 += e1_; oa1 = fmaf(e1_, (pw), oa1); \
    sa2 += e2_; oa2 = fmaf(e2_, (pw), oa2); \
    sa3 += e3_; oa3 = fmaf(e3_, (pw), oa3); }
#define ELM4(u, pw, jj) { \
    float e0_ = __builtin_amdgcn_exp2f(fmaf(t20, (u), -M20)); \
    float e1_ = __builtin_amdgcn_exp2f(fmaf(t21, (u), -M21)); \
    float e2_ = __builtin_amdgcn_exp2f(fmaf(t22, (u), -M22)); \
    float e3_ = __builtin_amdgcn_exp2f(fmaf(t23, (u), -M23)); \
    e0_ = ((jj) <= i0) ? e0_ : 0.f; \
    e1_ = ((jj) <= i1) ? e1_ : 0.f; \
    e2_ = ((jj) <= i2) ? e2_ : 0.f; \
    e3_ = ((jj) <= i3) ? e3_ : 0.f; \
    sa0 += e0_; oa0 = fmaf(e0_, (pw), oa0); \
    sa1 += e1_; oa1 = fmaf(e1_, (pw), oa1); \
    sa2 += e2_; oa2 = fmaf(e2_, (pw), oa2); \
    sa3 += e3_; oa3 = fmaf(e3_, (pw), oa3); }
#define ROT() { \
    float Cn_ = fmaf(S, sd, C * cd); \
    float Sn_ = fmaf(S, cd, -(C * sd)); \
    C = Cn_; S = Sn_; }

    // register double-buffer: prefetch next iteration's tiles at loop top
    float4 av = *(const float4*)&As[jb];
    float4 wv = *(const float4*)&Ws[jb];
    int t = 0;
    for (; t < ncom; ++t) {
        float4 avn = *(const float4*)&As[jb + 256];
        float4 wvn = *(const float4*)&Ws[jb + 256];
        float C1 = fmaf(S, sk1, C * ck1);
        float C2 = fmaf(S, sk2, C * ck2);
        float C3 = fmaf(S, sk3, C * ck3);
        float u0 = av.x * C,  u1 = av.y * C1;
        float u2 = av.z * C2, u3 = av.w * C3;
        EL4(u0, wv.x) EL4(u1, wv.y) EL4(u2, wv.z) EL4(u3, wv.w)
        ROT();
        av = avn; wv = wvn; jb += 256;
    }
    for (; t < T; ++t) {
        float4 avn = *(const float4*)&As[jb + 256];
        float4 wvn = *(const float4*)&Ws[jb + 256];
        float C1 = fmaf(S, sk1, C * ck1);
        float C2 = fmaf(S, sk2, C * ck2);
        float C3 = fmaf(S, sk3, C * ck3);
        float u0 = av.x * C,  u1 = av.y * C1;
        float u2 = av.z * C2, u3 = av.w * C3;
        ELM4(u0, wv.x, jb)     ELM4(u1, wv.y, jb + 1)
        ELM4(u2, wv.z, jb + 2) ELM4(u3, wv.w, jb + 3)
        ROT();
        av = avn; wv = wvn; jb += 256;
    }
#undef EL4
#undef ELM4
#undef ROT

    float S0 = wave_sum_dpp(sa0), O0 = wave_sum_dpp(oa0);
    float S1 = wave_sum_dpp(sa1), O1 = wave_sum_dpp(oa1);
    float S2 = wave_sum_dpp(sa2), O2 = wave_sum_dpp(oa2);
    float S3 = wave_sum_dpp(sa3), O3 = wave_sum_dpp(oa3);

    if (lane == 63) {
#define EPI(Sk, Ok, ik, xvk) if ((ik) < SEQ_L) { \
    float o0_ = (Ok) * __builtin_amdgcn_rcpf(Sk); \
    float h0_ = (xvk).x, h1_ = (xvk).y + o0_; \
    float inv_ = __builtin_amdgcn_rsqf(fmaf(h0_, h0_*0.5f, fmaf(h1_, h1_*0.5f, 1e-6f))); \
    float hn0_ = h0_ * inv_, hn1_ = h1_ * inv_; \
    float g0_ = hn0_ * ga + hn1_ * gc; \
    float g1_ = hn0_ * (ga - gc * 1e-3f) + hn1_ * gc; \
    float sg0_ = __builtin_amdgcn_rcpf(1.f + __builtin_amdgcn_exp2f(-g0_ * LOG2E)); \
    float sg1_ = __builtin_amdgcn_rcpf(1.f + __builtin_amdgcn_exp2f(-g1_ * LOG2E)); \
    float y1_ = cw * (g1_ * sg1_ - g0_ * sg0_) * hn0_; \
    outp[ik] = make_float2(h0_, h1_ + y1_); }
        EPI(S0, O0, i0, xv0)
        EPI(S1, O1, i1, xv1)
        EPI(S2, O2, i2, xv2)
        EPI(S3, O3, i3, xv3)
#undef EPI
    }
}

__global__ __launch_bounds__(256, 4) void attn_rows_kernel(
    const float* __restrict__ x,
    const float* __restrict__ q_weight,
    const float* __restrict__ v_weight,
    const float* __restrict__ gate_weight,
    const float* __restrict__ carry_weight,
    float* __restrict__ out,
    float scaleL2,
    float cd, float sd,
    float ck1, float sk1, float ck2, float sk2, float ck3, float sk3)
{
    __shared__ float As[SEQ_L + LDS_PAD];
    __shared__ float Ws[SEQ_L + LDS_PAD];

    const int tid  = threadIdx.x;
    const int lane = tid & 63;
    const int wave = tid >> 6;
    const int bat  = blockIdx.x / 129;
    const int bb   = blockIdx.x % 129;

    const float phi = q_weight[0];
    const float vw  = v_weight[0];
    const float2* x2 = (const float2*)x + (size_t)bat * SEQ_L;
    float2* outp = (float2*)out + (size_t)bat * SEQ_L;

    const float INV2PI = 0.15915494309189535f;
    const float rphi = phi * INV2PI;
    const float cphi = __builtin_amdgcn_cosf(rphi);
    const float sphi = __builtin_amdgcn_sinf(rphi);

    // Stage a_j / w_j (fp32) via 8 independent float4 loads per thread
    const float4* x4 = (const float4*)x2;
    #pragma unroll
    for (int it = 0; it < 8; ++it) {
        int idx = tid + (it << 8);           // float4 index, 0..2047
        float4 v = x4[idx];
        int e0 = idx << 1, e1 = e0 + 1;
        float inv0 = __builtin_amdgcn_rsqf(fmaf(v.x, v.x*0.5f, fmaf(v.y, v.y*0.5f, 1e-6f)));
        float xn0a = v.x * inv0;
        As[e0] = xn0a * __builtin_amdgcn_rsqf(fmaf(xn0a, xn0a*0.5f, 1e-6f));
        Ws[e0] = v.y * inv0 * vw;
        float inv1 = __builtin_amdgcn_rsqf(fmaf(v.z, v.z*0.5f, fmaf(v.w, v.w*0.5f, 1e-6f)));
        float xn0b = v.z * inv1;
        As[e1] = xn0b * __builtin_amdgcn_rsqf(fmaf(xn0b, xn0b*0.5f, 1e-6f));
        Ws[e1] = v.w * inv1 * vw;
    }
    __syncthreads();

    const int p = bb * 4 + wave;             // pair index
    if (p >= 513) return;

    const float ga = gate_weight[0];
    const float gc = gate_weight[1];
    const float cw = carry_weight[0];

    const int m = p / 19;
    const int c = p - 19 * m;
    const int b0A = 76 * m + c;              // light group (b0 <= 1994)
    const int b0B = 4046 - b0A;              // mirror heavy group (>= 2052)

    do_group(b0A, lane, x2, As, Ws, outp, scaleL2, cphi, sphi,
             cd, sd, ck1, sk1, ck2, sk2, ck3, sk3, ga, gc, cw);
    do_group(b0B, lane, x2, As, Ws, outp, scaleL2, cphi, sphi,
             cd, sd, ck1, sk1, ck2, sk2, ck3, sk3, ga, gc, cw);
}

extern "C" void kernel_launch(void* const* d_in, const int* in_sizes, int n_in,
                              void* d_out, int out_size, void* d_ws, size_t ws_size,
                              hipStream_t stream)
{
    const float* x  = (const float*)d_in[0];
    // d_in[1] = mask — causality handled analytically, unused
    const float* qw = (const float*)d_in[2];
    const float* vw = (const float*)d_in[3];
    const float* gw = (const float*)d_in[4];
    const float* cw = (const float*)d_in[5];
    float* out = (float*)d_out;

    const double omega = 2.0 * M_PI / 19.0;
    const double amp   = log(10.0) / (cos(omega * 0.3) - cos(omega * 0.7));
    const double qkns2 = amp / sqrt(2.0);               // QK_NORM_SCALE^2
    const double scale = pow(2.0, -0.5) * qkns2;        // HEAD_DIM^-0.5 * QK_NORM_SCALE^2
    const double L2E   = 1.4426950408889634074;
    const double delta = 256.0 * omega;                 // per-iteration angle decrement

    attn_rows_kernel<<<dim3(4 * 129), dim3(256), 0, stream>>>(
        x, qw, vw, gw, cw, out,
        (float)(scale * L2E),
        (float)cos(delta),       (float)sin(delta),
        (float)cos(omega),       (float)sin(omega),
        (float)cos(2.0 * omega), (float)sin(2.0 * omega),
        (float)cos(3.0 * omega), (float)sin(3.0 * omega));
}